// Round 1
// baseline (1100.470 us; speedup 1.0000x reference)
//
#include <hip/hip_runtime.h>
#include <stdint.h>

#define HD 2048
#define NTOK 4096
#define NROUTED 7
#define NEXP 8
#define ROWS_ROUTED 8192   // 2*NTOK (top-2, exact)
#define ROWS_TOTAL 12288   // + shared 4096
#define ROWS_PAD 12416     // +128 slack for tile overshoot

typedef __attribute__((ext_vector_type(8))) __bf16 bf16x8;
typedef __attribute__((ext_vector_type(4))) float f32x4;
typedef __attribute__((ext_vector_type(8))) unsigned short u16x8;

__device__ __forceinline__ float bf2f(unsigned short h) {
  union { unsigned int u; float f; } x; x.u = ((unsigned int)h) << 16; return x.f;
}
__device__ __forceinline__ unsigned short f2bf(float f) {
  union { float f; unsigned int u; } x; x.f = f;
  unsigned int r = x.u + 0x7fffu + ((x.u >> 16) & 1u);   // RNE
  return (unsigned short)(r >> 16);
}

// ---- async global->LDS, 16B/lane. LDS dest is wave-uniform base + lane*16.
__device__ __forceinline__ void async16(const void* g, void* l) {
  __builtin_amdgcn_global_load_lds(
      (__attribute__((address_space(1))) const void*)(uintptr_t)g,
      (__attribute__((address_space(3))) void*)(unsigned int)(uintptr_t)l,
      16, 0, 0);
}

// ---------------- elementwise fp32 -> bf16 ----------------
__global__ __launch_bounds__(256) void k_convert_bf16(const float* __restrict__ in,
                                                      unsigned short* __restrict__ out, int n) {
  int i = (blockIdx.x * 256 + threadIdx.x) * 4;
  if (i >= n) return;
  float4 v = *(const float4*)(in + i);
  ushort4 o; o.x = f2bf(v.x); o.y = f2bf(v.y); o.z = f2bf(v.z); o.w = f2bf(v.w);
  *(ushort4*)(out + i) = o;
}

// ---------------- transpose + convert: in [2048][2048] f32 -> out [2048][2048] bf16 = in^T
__global__ __launch_bounds__(256) void k_transpose_bf16(const float* __restrict__ in,
                                                        unsigned short* __restrict__ out) {
  __shared__ float tile[32][33];
  const size_t bs = (size_t)HD * HD;
  in += (size_t)blockIdx.z * bs; out += (size_t)blockIdx.z * bs;
  int x = threadIdx.x & 31, y = threadIdx.x >> 5;          // 32 x 8
  int r0 = blockIdx.y * 32, c0 = blockIdx.x * 32;
  #pragma unroll
  for (int i = 0; i < 4; i++) tile[y + 8*i][x] = in[(size_t)(r0 + y + 8*i) * HD + c0 + x];
  __syncthreads();
  #pragma unroll
  for (int i = 0; i < 4; i++) out[(size_t)(c0 + y + 8*i) * HD + r0 + x] = f2bf(tile[x][y + 8*i]);
}

// ---------------- router: gate = x@Wr + br; top-2 on gate+gate_bias; softmax of selected logits
// ctrl layout: [0..7]=counts, [8..15]=offsets, [16..23]=cursors
__global__ __launch_bounds__(256) void k_router(const float* __restrict__ x, const float* __restrict__ Wr,
                                                const float* __restrict__ br, const float* __restrict__ gbias,
                                                int* __restrict__ ids, float* __restrict__ wts,
                                                int* __restrict__ ctrl) {
  int lane = threadIdx.x & 63, wid = threadIdx.x >> 6;
  int t = blockIdx.x * 4 + wid;
  const float* xr = x + (size_t)t * HD;
  float acc[NROUTED];
  #pragma unroll
  for (int e = 0; e < NROUTED; e++) acc[e] = 0.f;
  for (int k = lane; k < HD; k += 64) {
    float xv = xr[k];
    const float* wrow = Wr + k * NROUTED;
    #pragma unroll
    for (int e = 0; e < NROUTED; e++) acc[e] += xv * wrow[e];
  }
  #pragma unroll
  for (int e = 0; e < NROUTED; e++) {
    #pragma unroll
    for (int off = 32; off > 0; off >>= 1) acc[e] += __shfl_down(acc[e], off);
  }
  if (lane == 0) {
    float lg[NROUTED], bg[NROUTED];
    #pragma unroll
    for (int e = 0; e < NROUTED; e++) { lg[e] = acc[e] + br[e]; bg[e] = lg[e] + gbias[e]; }
    int i1 = 0;
    #pragma unroll
    for (int e = 1; e < NROUTED; e++) if (bg[e] > bg[i1]) i1 = e;   // ties -> lowest idx
    int i2 = (i1 == 0) ? 1 : 0;
    #pragma unroll
    for (int e = 0; e < NROUTED; e++) if (e != i1 && bg[e] > bg[i2]) i2 = e;
    float l1 = lg[i1], l2 = lg[i2];
    float m = fmaxf(l1, l2);
    float p1 = __expf(l1 - m), p2 = __expf(l2 - m);
    float s = p1 + p2;
    ids[2*t] = i1; ids[2*t+1] = i2;
    wts[2*t] = p1 / s; wts[2*t+1] = p2 / s;
    atomicAdd(&ctrl[i1], 1); atomicAdd(&ctrl[i2], 1);
  }
}

__global__ void k_offsets(int* ctrl) {
  if (threadIdx.x == 0 && blockIdx.x == 0) {
    ctrl[7] = NTOK;                 // shared expert "count"
    int o = 0;
    #pragma unroll
    for (int e = 0; e < NEXP; e++) { ctrl[8 + e] = o; o += ctrl[e]; }  // offs[7] == 8192 always
  }
}

__global__ __launch_bounds__(256) void k_build_lists(const int* __restrict__ ids, int* __restrict__ ctrl,
                                                     int* __restrict__ tok_list, int* __restrict__ tok_pos) {
  int t = blockIdx.x * 256 + threadIdx.x;
  if (t >= NTOK) return;
  #pragma unroll
  for (int j = 0; j < 2; j++) {
    int e = ids[2*t + j];
    int pos = ctrl[8 + e] + atomicAdd(&ctrl[16 + e], 1);
    tok_list[pos] = t;
    tok_pos[2*t + j] = pos;
  }
  tok_list[ROWS_ROUTED + t] = t;    // identity list for shared expert
}

// ---------------- grouped GEMM, 128x128 tile, BK=32, 4 waves, 16x16x32 bf16 MFMA
// MODE 0: u  = gather(x) @ WupT  + bup          (A rows gathered via tok_list)
// MODE 1: g  = silu(u @ WgateT + bgate) * u     (A = u packed rows; epilogue reads u)
// MODE 2: eo = g @ WdownT + bdown               (A = g packed rows)
template<int MODE>
__global__ __launch_bounds__(256) void k_moe_gemm(
    const unsigned short* __restrict__ Abase,
    const unsigned short* __restrict__ WTr,   // [7][N=2048][K=2048] bf16 (pre-transposed)
    const unsigned short* __restrict__ WTs,   // [2048][2048]
    const float* __restrict__ biasR,          // [7][2048]
    const float* __restrict__ biasS,          // [2048]
    const int* __restrict__ ctrl,
    const int* __restrict__ tok_list,
    const unsigned short* __restrict__ Uep,   // u (MODE 1 only)
    unsigned short* __restrict__ Out)         // bf16 [ROWS_PAD][2048]
{
  const int e   = blockIdx.z;
  const int cnt = ctrl[e];
  const int m0  = blockIdx.y * 128;
  if (m0 >= cnt) return;
  const int off = ctrl[8 + e];
  const int n0  = blockIdx.x * 128;

  const unsigned short* W = (e < NROUTED) ? (WTr + (size_t)e * HD * HD) : WTs;
  const float* bias = (e < NROUTED) ? (biasR + e * HD) : biasS;

  __shared__ __align__(16) unsigned short As[128 * 32];
  __shared__ __align__(16) unsigned short Bs[128 * 32];

  const int tid  = threadIdx.x;
  const int lane = tid & 63;
  const int wid  = tid >> 6;

  // staging: per round (2 rounds per matrix) thread covers row = r*64 + tid/4, k-off (tid&3)*8
  const int srow = tid >> 2;
  const int skel = (tid & 3) * 8;

  int ar0 = m0 + srow, ar1 = m0 + 64 + srow;
  size_t ga0, ga1;
  if (MODE == 0) {
    int c1 = cnt - 1;
    int t0 = tok_list[off + (ar0 < cnt ? ar0 : c1)];
    int t1 = tok_list[off + (ar1 < cnt ? ar1 : c1)];
    ga0 = (size_t)t0 * HD; ga1 = (size_t)t1 * HD;
  } else {
    ga0 = (size_t)(off + ar0) * HD; ga1 = (size_t)(off + ar1) * HD;
  }
  const unsigned short* pA0 = Abase + ga0 + skel;
  const unsigned short* pA1 = Abase + ga1 + skel;
  const unsigned short* pB0 = W + (size_t)(n0 + srow) * HD + skel;
  const unsigned short* pB1 = W + (size_t)(n0 + 64 + srow) * HD + skel;

  unsigned short* lA0 = As + wid * 512;          // round 0: wave-uniform base (1024B/wave)
  unsigned short* lA1 = As + 2048 + wid * 512;   // round 1
  unsigned short* lB0 = Bs + wid * 512;
  unsigned short* lB1 = Bs + 2048 + wid * 512;

  const int wm = (wid >> 1) * 64;
  const int wn = (wid & 1) * 64;
  const int rm = lane & 15;
  const int kq = (lane >> 4) * 8;

  f32x4 zero = {0.f, 0.f, 0.f, 0.f};
  f32x4 acc[4][4];
  #pragma unroll
  for (int i = 0; i < 4; i++)
    #pragma unroll
    for (int j = 0; j < 4; j++) acc[i][j] = zero;

  for (int k0 = 0; k0 < HD; k0 += 32) {
    __syncthreads();                     // previous iter's LDS reads done
    async16(pA0, lA0); async16(pA1, lA1);
    async16(pB0, lB0); async16(pB1, lB1);
    pA0 += 32; pA1 += 32; pB0 += 32; pB1 += 32;
    __syncthreads();                     // drains vmcnt: LDS tiles ready
    bf16x8 af[4], bfr[4];
    #pragma unroll
    for (int mi = 0; mi < 4; mi++) af[mi]  = *(const bf16x8*)(As + (wm + mi*16 + rm) * 32 + kq);
    #pragma unroll
    for (int ni = 0; ni < 4; ni++) bfr[ni] = *(const bf16x8*)(Bs + (wn + ni*16 + rm) * 32 + kq);
    #pragma unroll
    for (int mi = 0; mi < 4; mi++)
      #pragma unroll
      for (int ni = 0; ni < 4; ni++)
        acc[mi][ni] = __builtin_amdgcn_mfma_f32_16x16x32_bf16(af[mi], bfr[ni], acc[mi][ni], 0, 0, 0);
  }

  // epilogue: C/D layout col=lane&15, row=(lane>>4)*4+reg  [verified m89/m91]
  const int quad = lane >> 4;
  #pragma unroll
  for (int mi = 0; mi < 4; mi++) {
    int rb = wm + mi * 16 + quad * 4;
    #pragma unroll
    for (int r = 0; r < 4; r++) {
      int gm = m0 + rb + r;
      if (gm < cnt) {
        size_t orow = (size_t)(off + gm) * HD;
        #pragma unroll
        for (int ni = 0; ni < 4; ni++) {
          int gn = n0 + wn + ni * 16 + rm;
          float v = acc[mi][ni][r] + bias[gn];
          if (MODE == 1) {
            float uv = bf2f(Uep[orow + gn]);
            float sg = v / (1.f + __expf(-v));   // silu
            v = sg * uv;
          }
          Out[orow + gn] = f2bf(v);
        }
      }
    }
  }
}

// ---------------- combine: out[t] = w0*eo[p0] + w1*eo[p1] + eo[8192+t]
__global__ __launch_bounds__(256) void k_combine(const unsigned short* __restrict__ eo,
                                                 const int* __restrict__ tok_pos,
                                                 const float* __restrict__ wts,
                                                 float* __restrict__ out) {
  int t = blockIdx.x;
  int h = threadIdx.x * 8;
  int p0 = tok_pos[2*t], p1 = tok_pos[2*t+1];
  float w0 = wts[2*t], w1 = wts[2*t+1];
  u16x8 a = *(const u16x8*)(eo + (size_t)p0 * HD + h);
  u16x8 b = *(const u16x8*)(eo + (size_t)p1 * HD + h);
  u16x8 c = *(const u16x8*)(eo + (size_t)(ROWS_ROUTED + t) * HD + h);
  float* o = out + (size_t)t * HD + h;
  #pragma unroll
  for (int i = 0; i < 8; i++) o[i] = w0 * bf2f(a[i]) + w1 * bf2f(b[i]) + bf2f(c[i]);
}

extern "C" void kernel_launch(void* const* d_in, const int* in_sizes, int n_in,
                              void* d_out, int out_size, void* d_ws, size_t ws_size,
                              hipStream_t stream) {
  (void)in_sizes; (void)n_in; (void)out_size; (void)ws_size;
  const float* x     = (const float*)d_in[0];
  const float* Wr    = (const float*)d_in[1];
  const float* br    = (const float*)d_in[2];
  const float* gbias = (const float*)d_in[3];
  const float* Wup   = (const float*)d_in[4];
  const float* bup   = (const float*)d_in[5];
  const float* Wgate = (const float*)d_in[6];
  const float* bgate = (const float*)d_in[7];
  const float* Wdown = (const float*)d_in[8];
  const float* bdown = (const float*)d_in[9];
  const float* Wsu   = (const float*)d_in[10];
  const float* bsu   = (const float*)d_in[11];
  const float* Wsg   = (const float*)d_in[12];
  const float* bsg   = (const float*)d_in[13];
  const float* Wsd   = (const float*)d_in[14];
  const float* bsd   = (const float*)d_in[15];
  float* out = (float*)d_out;

  char* ws = (char*)d_ws;
  size_t o = 0;
  auto alloc = [&](size_t bytes) { char* p = ws + o; o += (bytes + 255) & ~(size_t)255; return p; };
  unsigned short* WT_r = (unsigned short*)alloc((size_t)7 * HD * HD * 2);  // reused per stage
  unsigned short* WT_s = (unsigned short*)alloc((size_t)HD * HD * 2);
  unsigned short* xbf  = (unsigned short*)alloc((size_t)NTOK * HD * 2);
  unsigned short* bufU = (unsigned short*)alloc((size_t)ROWS_PAD * HD * 2); // u, later eo
  unsigned short* bufG = (unsigned short*)alloc((size_t)ROWS_PAD * HD * 2); // g
  int*   ctrl     = (int*)alloc(4096);
  int*   ids      = (int*)alloc(NTOK * 2 * 4);
  float* wts      = (float*)alloc(NTOK * 2 * 4);
  int*   tok_list = (int*)alloc(ROWS_TOTAL * 4);
  int*   tok_pos  = (int*)alloc(NTOK * 2 * 4);
  // total ~186 MB

  hipMemsetAsync(ctrl, 0, 96, stream);
  k_convert_bf16<<<NTOK * HD / 1024, 256, 0, stream>>>(x, xbf, NTOK * HD);
  k_router<<<NTOK / 4, 256, 0, stream>>>(x, Wr, br, gbias, ids, wts, ctrl);
  k_offsets<<<1, 64, 0, stream>>>(ctrl);
  k_build_lists<<<NTOK / 256, 256, 0, stream>>>(ids, ctrl, tok_list, tok_pos);

  dim3 tgrid(HD / 32, HD / 32, 7), tgrid1(HD / 32, HD / 32, 1);
  dim3 ggrid(HD / 128, 32, 8);

  k_transpose_bf16<<<tgrid, 256, 0, stream>>>(Wup, WT_r);
  k_transpose_bf16<<<tgrid1, 256, 0, stream>>>(Wsu, WT_s);
  k_moe_gemm<0><<<ggrid, 256, 0, stream>>>(xbf, WT_r, WT_s, bup, bsu, ctrl, tok_list, nullptr, bufU);

  k_transpose_bf16<<<tgrid, 256, 0, stream>>>(Wgate, WT_r);
  k_transpose_bf16<<<tgrid1, 256, 0, stream>>>(Wsg, WT_s);
  k_moe_gemm<1><<<ggrid, 256, 0, stream>>>(bufU, WT_r, WT_s, bgate, bsg, ctrl, tok_list, bufU, bufG);

  k_transpose_bf16<<<tgrid, 256, 0, stream>>>(Wdown, WT_r);
  k_transpose_bf16<<<tgrid1, 256, 0, stream>>>(Wsd, WT_s);
  k_moe_gemm<2><<<ggrid, 256, 0, stream>>>(bufG, WT_r, WT_s, bdown, bsd, ctrl, tok_list, nullptr, bufU);

  k_combine<<<NTOK, 256, 0, stream>>>(bufU, tok_pos, wts, out);
}